// Round 8
// baseline (53.372 us; speedup 1.0000x reference)
//
#include <hip/hip_runtime.h>
#include <stdint.h>

typedef unsigned int u32;

#define NACC   31
#define NSHIFT 15
#define ROWB   4096     // bytes per (c,b) row: 2048 positions * 2 planes
#define NBLK   2048     // 2048 blocks * 4 waves = 8192 waves, 1 row each
#define NSH    32       // shadow copies of each counter

// 16 input bytes = positions 8k..8k+7, byte 2i = plane0, 2i+1 = plane1.
// Returns plane0 bits [7:0] | plane1 bits [15:8]  (bit b = position 8k+b).
// 0/1-byte->bit: (b0|b1<<8|b2<<16|b3<<24)*0x01020408 puts b0..b3 at bits
// 24..27 carry-free.
__device__ __forceinline__ u32 chunk16(uint4 v) {
    const u32 q0 = __byte_perm(v.x, v.y, 0x6420);   // plane0 +0..3
    const u32 q1 = __byte_perm(v.x, v.y, 0x7531);   // plane1 +0..3
    const u32 q2 = __byte_perm(v.z, v.w, 0x6420);   // plane0 +4..7
    const u32 q3 = __byte_perm(v.z, v.w, 0x7531);   // plane1 +4..7
    const u32 n0 = (q0 * 0x01020408u) >> 24;
    const u32 n1 = (q1 * 0x01020408u) >> 24;
    const u32 n2 = (q2 * 0x01020408u) >> 24;
    const u32 n3 = (q3 * 0x01020408u) >> 24;
    return (n0 | (n2 << 4)) | ((n1 | (n3 << 4)) << 8);
}

// From the 4 coalesced chunk16 results (t=0..3), build per-plane byte-planes:
// PL0 byte t = plane0 chunk (64t + lane), PL1 byte t = plane1 chunk (64t+lane).
__device__ __forceinline__ void packarr(const uint4 s[4], u32& PL0, u32& PL1) {
    const u32 c0 = chunk16(s[0]), c1 = chunk16(s[1]);
    const u32 c2 = chunk16(s[2]), c3 = chunk16(s[3]);
    const u32 lo01 = __byte_perm(c0, c1, 0x5410);   // p0t0,p1t0,p0t1,p1t1
    const u32 lo23 = __byte_perm(c2, c3, 0x5410);
    PL0 = __byte_perm(lo01, lo23, 0x6420);
    PL1 = __byte_perm(lo01, lo23, 0x7531);
}

// Register transpose: lane l's word = chunks 4l..4l+3 (byte i = chunk 4l+i),
// chunk k lives at lane k&63, byte slot k>>6 (= l>>4 for k=4l+i).
// 4 ds_bpermute + 3 v_perm per plane; selE = (l>>4) | ((l>>4)+4)<<4.
__device__ __forceinline__ void xpose(u32 PL, int s0, u32 selE, u32& W) {
    const u32 g0 = __shfl(PL, s0, 64),     g1 = __shfl(PL, s0 + 1, 64);
    const u32 g2 = __shfl(PL, s0 + 2, 64), g3 = __shfl(PL, s0 + 3, 64);
    const u32 p01 = __byte_perm(g0, g1, selE);      // b0=g0[e], b1=g1[e]
    const u32 p23 = __byte_perm(g2, g3, selE);
    W = __byte_perm(p01, p23, 0x5410);
}

// One wave per row. Lane l owns positions 32l..32l+31 per plane (u32,
// bit j = position 32l+j); ring = the 64-lane wave; |s|<=15 < 32 so a
// rotation needs only lane+-1 words. Global loads are fully coalesced
// (lane l -> uint4 index 64t+l, 1KB contiguous per instruction); ownership
// is restored by the in-register shuffle transpose above. No LDS in the
// main loop (rounds 5/7 lesson: stride-64 LDS transpose = 32-way conflict).
// No device-scope fences (round-4 lesson: per-block __threadfence on CDNA4
// = L2 writeback storm).
__global__ __launch_bounds__(256, 4) void hd_main(
    const unsigned char* __restrict__ ia, const unsigned char* __restrict__ ma,
    const unsigned char* __restrict__ ib, const unsigned char* __restrict__ mb,
    u32* __restrict__ cnt)
{
    const int tid  = threadIdx.x;
    const int lane = tid & 63;
    const int wv   = tid >> 6;
    const int row  = blockIdx.x * 4 + wv;        // 0..8191

    const size_t rb = (size_t)row * ROWB;
    const uint4* pa = (const uint4*)(ia + rb);
    const uint4* pm = (const uint4*)(ma + rb);
    const uint4* pb = (const uint4*)(ib + rb);
    const uint4* pn = (const uint4*)(mb + rb);

    // ---- issue all 16 coalesced loads (SGPR base + lane*16 + imm t*1024) --
    uint4 sA[4], sM[4], sB[4], sN[4];
#pragma unroll
    for (int t = 0; t < 4; ++t) sA[t] = pa[t * 64 + lane];
#pragma unroll
    for (int t = 0; t < 4; ++t) sM[t] = pm[t * 64 + lane];
#pragma unroll
    for (int t = 0; t < 4; ++t) sB[t] = pb[t * 64 + lane];
#pragma unroll
    for (int t = 0; t < 4; ++t) sN[t] = pn[t * 64 + lane];

    // ---- pack + transpose to lane-owned bit rings ----
    const int s0   = (lane << 2) & 63;           // source lane group
    const u32 e    = (u32)(lane >> 4);           // byte slot
    const u32 selE = e | ((e + 4u) << 4);

    u32 A0, A1, M0, M1, B0, B1, N0, N1;
    {
        u32 L0, L1;
        packarr(sA, L0, L1); xpose(L0, s0, selE, A0); xpose(L1, s0, selE, A1);
        packarr(sM, L0, L1); xpose(L0, s0, selE, M0); xpose(L1, s0, selE, M1);
        packarr(sB, L0, L1); xpose(L0, s0, selE, B0); xpose(L1, s0, selE, B1);
        packarr(sN, L0, L1); xpose(L0, s0, selE, N0); xpose(L1, s0, selE, N1);
    }

    u32 acc[NACC];                               // num | den<<16 per shift
#pragma unroll
    for (int j = 0; j < NACC; ++j) acc[j] = 0u;

    const int prevL = (lane + 63) & 63;
    const int nextL = (lane + 1) & 63;
    const u32 pA0 = __shfl(A0, prevL, 64), pA1 = __shfl(A1, prevL, 64);
    const u32 pM0 = __shfl(M0, prevL, 64), pM1 = __shfl(M1, prevL, 64);
    const u32 nA0 = __shfl(A0, nextL, 64), nA1 = __shfl(A1, nextL, 64);
    const u32 nM0 = __shfl(M0, nextL, 64), nM1 = __shfl(M1, nextL, 64);

    {   // s = 0 (j = 15)
        const u32 k0 = M0 & N0, k1 = M1 & N1;
        const u32 nm = __popc((A0 ^ B0) & k0) + __popc((A1 ^ B1) & k1);
        const u32 dn = __popc(k0) + __popc(k1);
        acc[15] += nm | (dn << 16);
    }
#pragma unroll
    for (int s = 1; s <= NSHIFT; ++s) {
        {   // roll right by s: rolled[p] = orig[p-s]  (j = 15+s)
            const u32 ra0 = (A0 << s) | (pA0 >> (32 - s));
            const u32 ra1 = (A1 << s) | (pA1 >> (32 - s));
            const u32 rm0 = (M0 << s) | (pM0 >> (32 - s));
            const u32 rm1 = (M1 << s) | (pM1 >> (32 - s));
            const u32 k0 = rm0 & N0, k1 = rm1 & N1;
            const u32 nm = __popc((ra0 ^ B0) & k0) + __popc((ra1 ^ B1) & k1);
            const u32 dn = __popc(k0) + __popc(k1);
            acc[15 + s] += nm | (dn << 16);
        }
        {   // roll left by s: rolled[p] = orig[p+s]   (j = 15-s)
            const u32 ra0 = (A0 >> s) | (nA0 << (32 - s));
            const u32 ra1 = (A1 >> s) | (nA1 << (32 - s));
            const u32 rm0 = (M0 >> s) | (nM0 << (32 - s));
            const u32 rm1 = (M1 >> s) | (nM1 << (32 - s));
            const u32 k0 = rm0 & N0, k1 = rm1 & N1;
            const u32 nm = __popc((ra0 ^ B0) & k0) + __popc((ra1 ^ B1) & k1);
            const u32 dn = __popc(k0) + __popc(k1);
            acc[15 - s] += nm | (dn << 16);
        }
    }

    // ---- per-wave half-butterfly, block reduce in LDS, shadowed atomics ----
    // per-lane fields <= 64; after 32-xor <= 128; block partials <= 16384.
    __shared__ alignas(16) u32 red[32][132];     // row 31 = dummy
#pragma unroll
    for (int j = 0; j < NACC; ++j) acc[j] += __shfl_xor(acc[j], 32, 64);
#pragma unroll
    for (int j = 0; j < NACC; j += 2) {
        const u32 v = (j + 1 < NACC && (lane & 32)) ? acc[j + 1] : acc[j];
        red[j + (lane >> 5)][wv * 32 + (lane & 31)] = v;
    }
    __syncthreads();

    if (tid < 248) {
        const int j = tid >> 3, c = tid & 7;     // 8 threads per counter j
        const uint4* p = (const uint4*)&red[j][c * 16];
        u32 sn = 0, sd = 0;
#pragma unroll
        for (int i = 0; i < 4; ++i) {
            const uint4 v = p[i];
            sn += (v.x & 0xFFFFu) + (v.y & 0xFFFFu) + (v.z & 0xFFFFu) + (v.w & 0xFFFFu);
            sd += (v.x >> 16) + (v.y >> 16) + (v.z >> 16) + (v.w >> 16);
        }
        sn += __shfl_xor(sn, 1, 64); sd += __shfl_xor(sd, 1, 64);
        sn += __shfl_xor(sn, 2, 64); sd += __shfl_xor(sd, 2, 64);
        sn += __shfl_xor(sn, 4, 64); sd += __shfl_xor(sd, 4, 64);
        if (c == 0) {
            const int sh = blockIdx.x & (NSH - 1);
            atomicAdd(&cnt[j * NSH + sh], sn);          // num_j
            atomicAdd(&cnt[(31 + j) * NSH + sh], sd);   // den_j
        }
    }
    // no fence: device-scope atomics + kernel boundary order the finalize.
}

// One block, 256 threads: fold 32 shadows per counter (vector loads),
// 31 divisions, min, clamp to 1.
__global__ void hd_finalize(const u32* __restrict__ cnt, float* __restrict__ out)
{
    __shared__ u32 gathered[62];
    const int tid = threadIdx.x;
    if (tid < 248) {
        const int j = tid >> 2, q = tid & 3;     // 4 threads per counter
        const uint4* p = (const uint4*)&cnt[j * NSH + q * 8];
        const uint4 v0 = p[0], v1 = p[1];
        u32 s = v0.x + v0.y + v0.z + v0.w + v1.x + v1.y + v1.z + v1.w;
        s += __shfl_xor(s, 1, 64);
        s += __shfl_xor(s, 2, 64);
        if (q == 0) gathered[j] = s;
    }
    __syncthreads();
    if (tid < 64) {
        float f = 1.0f;
        if (tid < NACC) f = (float)gathered[tid] / (float)gathered[31 + tid];
#pragma unroll
        for (int o = 32; o > 0; o >>= 1) f = fminf(f, __shfl_xor(f, o, 64));
        if (tid == 0) out[0] = fminf(f, 1.0f);
    }
}

extern "C" void kernel_launch(void* const* d_in, const int* in_sizes, int n_in,
                              void* d_out, int out_size, void* d_ws, size_t ws_size,
                              hipStream_t stream)
{
    const unsigned char* ia = (const unsigned char*)d_in[0];  // iris_codes_a
    const unsigned char* ma = (const unsigned char*)d_in[1];  // mask_codes_a
    const unsigned char* ib = (const unsigned char*)d_in[2];  // iris_codes_b
    const unsigned char* mb = (const unsigned char*)d_in[3];  // mask_codes_b
    u32* cnt = (u32*)d_ws;                    // [62][32] shadow counters

    hipMemsetAsync(d_ws, 0, 62 * NSH * sizeof(u32), stream);
    hd_main<<<dim3(NBLK), dim3(256), 0, stream>>>(ia, ma, ib, mb, cnt);
    hd_finalize<<<dim3(1), dim3(256), 0, stream>>>(cnt, (float*)d_out);
}

// Round 9
// 49.065 us; speedup vs baseline: 1.0878x; 1.0878x over previous
//
#include <hip/hip_runtime.h>
#include <stdint.h>

typedef unsigned int u32;
typedef unsigned long long u64;

#define NACC   31
#define NSHIFT 15
#define ROWB   4096     // bytes per (c,b) row: 2048 positions * 2 planes
#define NBLK   2048     // 2048 blocks * 4 waves = 8192 waves, 1 row each
#define NSH    32       // shadow copies of each counter

// repeat a byte value across all 8 byte lanes (compile-time)
__device__ __forceinline__ u64 rep8(u32 b) { return (u64)b * 0x0101010101010101ULL; }
__device__ __forceinline__ u64 rotl16_64(u64 x) { return (x << 16) | (x >> 48); }
__device__ __forceinline__ u64 rotr16_64(u64 x) { return (x >> 16) | (x << 48); }

// 16 input bytes = chunk k (positions 8k..8k+7), byte 2i = plane0(8k+i),
// byte 2i+1 = plane1(8k+i). Returns p0 bits[7:0] | p1 bits[15:8], bit i = pos 8k+i.
// 0/1-byte->bit: (b0|b1<<8|b2<<16|b3<<24)*0x01020408 puts b0..b3 at bits 24..27.
__device__ __forceinline__ u32 chunk16(uint4 v) {
    const u32 q0 = __byte_perm(v.x, v.y, 0x6420);   // plane0 +0..3
    const u32 q1 = __byte_perm(v.x, v.y, 0x7531);   // plane1 +0..3
    const u32 q2 = __byte_perm(v.z, v.w, 0x6420);   // plane0 +4..7
    const u32 q3 = __byte_perm(v.z, v.w, 0x7531);   // plane1 +4..7
    const u32 n0 = (q0 * 0x01020408u) >> 24;
    const u32 n1 = (q1 * 0x01020408u) >> 24;
    const u32 n2 = (q2 * 0x01020408u) >> 24;
    const u32 n3 = (q3 * 0x01020408u) >> 24;
    return (n0 | (n2 << 4)) | ((n1 | (n3 << 4)) << 8);
}

// Pack 4 coalesced chunks (t=0..3) into a u64: 16-bit slot t = chunk 64t+lane.
__device__ __forceinline__ u64 pk4(const uint4 s[4]) {
    const u32 c0 = chunk16(s[0]), c1 = chunk16(s[1]);
    const u32 c2 = chunk16(s[2]), c3 = chunk16(s[3]);
    const u32 lo = __byte_perm(c0, c1, 0x5410);     // c0 | c1<<16
    const u32 hi = __byte_perm(c2, c3, 0x5410);     // c2 | c3<<16
    return (u64)lo | ((u64)hi << 32);
}

__device__ __forceinline__ u64 shfl64(u64 v, int src) {
    return (u64)__shfl((long long)v, src, 64);
}

// One wave per row, COALESCED layout kept end-to-end (no transpose, no LDS
// in the hot path — rounds 5/7/8 lesson: every transpose mechanism cost more
// than the strided-load pattern it fixed). Lane l holds chunks {64t+l} of the
// 256-chunk ring as u64 slots; chunk k-1 = lane l-1's slot t (lane-wrap
// handled by a 16-bit rotate on lanes 0/1/62/63). A roll by |s|<=15 is a
// byte-wise funnel shift using chunk words from lanes l-2..l+2 (8 u64 shfls
// per row, A and M only). No device-scope fences (round-4 lesson).
__global__ __launch_bounds__(256) void hd_main(
    const unsigned char* __restrict__ ia, const unsigned char* __restrict__ ma,
    const unsigned char* __restrict__ ib, const unsigned char* __restrict__ mb,
    u32* __restrict__ cnt)
{
    const int tid  = threadIdx.x;
    const int lane = tid & 63;
    const int wv   = tid >> 6;
    const int row  = blockIdx.x * 4 + wv;        // 0..8191

    const size_t rb = (size_t)row * ROWB;
    const uint4* pa = (const uint4*)(ia + rb);
    const uint4* pm = (const uint4*)(ma + rb);
    const uint4* pb = (const uint4*)(ib + rb);
    const uint4* pn = (const uint4*)(mb + rb);

    // ---- 16 fully-coalesced loads (lane l -> uint4 64t+l, 1KB/instr) ----
    uint4 sA[4], sM[4], sB[4], sN[4];
#pragma unroll
    for (int t = 0; t < 4; ++t) sA[t] = pa[t * 64 + lane];
#pragma unroll
    for (int t = 0; t < 4; ++t) sM[t] = pm[t * 64 + lane];
#pragma unroll
    for (int t = 0; t < 4; ++t) sB[t] = pb[t * 64 + lane];
#pragma unroll
    for (int t = 0; t < 4; ++t) sN[t] = pn[t * 64 + lane];

    const u64 CA = pk4(sA);
    const u64 CM = pk4(sM);
    const u64 CB = pk4(sB);
    const u64 CN = pk4(sN);

    // ---- neighbor chunk words for A and M (ring: chunk k +- 1, 2) ----
    const int lm1 = (lane + 63) & 63, lm2 = (lane + 62) & 63;
    const int lp1 = (lane + 1) & 63,  lp2 = (lane + 2) & 63;

    u64 PA1 = shfl64(CA, lm1), PA2 = shfl64(CA, lm2);
    u64 PM1 = shfl64(CM, lm1), PM2 = shfl64(CM, lm2);
    u64 NA1 = shfl64(CA, lp1), NA2 = shfl64(CA, lp2);
    u64 NM1 = shfl64(CM, lp1), NM2 = shfl64(CM, lp2);
    // lane-boundary slot realignment (chunk index crosses a 64-chunk block)
    if (lane == 0)  { PA1 = rotl16_64(PA1); PM1 = rotl16_64(PM1); }
    if (lane <= 1)  { PA2 = rotl16_64(PA2); PM2 = rotl16_64(PM2); }
    if (lane == 63) { NA1 = rotr16_64(NA1); NM1 = rotr16_64(NM1); }
    if (lane >= 62) { NA2 = rotr16_64(NA2); NM2 = rotr16_64(NM2); }

    u32 acc[NACC];                               // num | den<<16 per shift
#pragma unroll
    for (int j = 0; j < NACC; ++j) acc[j] = 0u;

    {   // s = 0 (j = 15)
        const u64 k = CM & CN;
        const u64 x = (CA ^ CB) & k;
        acc[15] += (u32)__popcll(x) | ((u32)__popcll(k) << 16);
    }
    // bytewise funnel shifts; masks are compile-time repeat-byte constants.
#pragma unroll
    for (int s = 1; s <= 8; ++s) {
        {   // roll right by s (j = 15+s): bits [s..7] from own, [0..s-1] prev
            const u64 m = rep8((0xFFu << s) & 0xFFu);
            const u64 rA = ((CA << s) & m) | ((PA1 >> (8 - s)) & ~m);
            const u64 rM = ((CM << s) & m) | ((PM1 >> (8 - s)) & ~m);
            const u64 k = rM & CN;
            const u64 x = (rA ^ CB) & k;
            acc[15 + s] += (u32)__popcll(x) | ((u32)__popcll(k) << 16);
        }
        {   // roll left by s (j = 15-s): bits [0..7-s] own, [8-s..7] next
            const u64 m = rep8(0xFFu >> s);
            const u64 lA = ((CA >> s) & m) | ((NA1 << (8 - s)) & ~m);
            const u64 lM = ((CM >> s) & m) | ((NM1 << (8 - s)) & ~m);
            const u64 k = lM & CN;
            const u64 x = (lA ^ CB) & k;
            acc[15 - s] += (u32)__popcll(x) | ((u32)__popcll(k) << 16);
        }
    }
#pragma unroll
    for (int s = 9; s <= 15; ++s) {
        {   // roll right by s: bits [s-8..7] from prev1, [0..s-9] from prev2
            const u64 m = rep8((0xFFu << (s - 8)) & 0xFFu);
            const u64 rA = ((PA1 << (s - 8)) & m) | ((PA2 >> (16 - s)) & ~m);
            const u64 rM = ((PM1 << (s - 8)) & m) | ((PM2 >> (16 - s)) & ~m);
            const u64 k = rM & CN;
            const u64 x = (rA ^ CB) & k;
            acc[15 + s] += (u32)__popcll(x) | ((u32)__popcll(k) << 16);
        }
        {   // roll left by s: bits [0..15-s] from next1, [16-s..7] from next2
            const u64 m = rep8(0xFFu >> (s - 8));
            const u64 lA = ((NA1 >> (s - 8)) & m) | ((NA2 << (16 - s)) & ~m);
            const u64 lM = ((NM1 >> (s - 8)) & m) | ((NM2 << (16 - s)) & ~m);
            const u64 k = lM & CN;
            const u64 x = (lA ^ CB) & k;
            acc[15 - s] += (u32)__popcll(x) | ((u32)__popcll(k) << 16);
        }
    }

    // ---- per-wave half-butterfly, block reduce in LDS, shadowed atomics ----
    // per-lane fields <= 64; after 32-xor <= 128; block partials <= 16384.
    __shared__ alignas(16) u32 red[32][132];     // row 31 = dummy
#pragma unroll
    for (int j = 0; j < NACC; ++j) acc[j] += __shfl_xor(acc[j], 32, 64);
#pragma unroll
    for (int j = 0; j < NACC; j += 2) {
        const u32 v = (j + 1 < NACC && (lane & 32)) ? acc[j + 1] : acc[j];
        red[j + (lane >> 5)][wv * 32 + (lane & 31)] = v;
    }
    __syncthreads();

    if (tid < 248) {
        const int j = tid >> 3, c = tid & 7;     // 8 threads per counter j
        const uint4* p = (const uint4*)&red[j][c * 16];
        u32 sn = 0, sd = 0;
#pragma unroll
        for (int i = 0; i < 4; ++i) {
            const uint4 v = p[i];
            sn += (v.x & 0xFFFFu) + (v.y & 0xFFFFu) + (v.z & 0xFFFFu) + (v.w & 0xFFFFu);
            sd += (v.x >> 16) + (v.y >> 16) + (v.z >> 16) + (v.w >> 16);
        }
        sn += __shfl_xor(sn, 1, 64); sd += __shfl_xor(sd, 1, 64);
        sn += __shfl_xor(sn, 2, 64); sd += __shfl_xor(sd, 2, 64);
        sn += __shfl_xor(sn, 4, 64); sd += __shfl_xor(sd, 4, 64);
        if (c == 0) {
            const int sh = blockIdx.x & (NSH - 1);
            atomicAdd(&cnt[j * NSH + sh], sn);          // num_j
            atomicAdd(&cnt[(31 + j) * NSH + sh], sd);   // den_j
        }
    }
    // no fence: device-scope atomics + kernel boundary order the finalize.
}

// One block, 256 threads: fold 32 shadows per counter (vector loads),
// 31 divisions, min, clamp to 1.
__global__ void hd_finalize(const u32* __restrict__ cnt, float* __restrict__ out)
{
    __shared__ u32 gathered[62];
    const int tid = threadIdx.x;
    if (tid < 248) {
        const int j = tid >> 2, q = tid & 3;     // 4 threads per counter
        const uint4* p = (const uint4*)&cnt[j * NSH + q * 8];
        const uint4 v0 = p[0], v1 = p[1];
        u32 s = v0.x + v0.y + v0.z + v0.w + v1.x + v1.y + v1.z + v1.w;
        s += __shfl_xor(s, 1, 64);
        s += __shfl_xor(s, 2, 64);
        if (q == 0) gathered[j] = s;
    }
    __syncthreads();
    if (tid < 64) {
        float f = 1.0f;
        if (tid < NACC) f = (float)gathered[tid] / (float)gathered[31 + tid];
#pragma unroll
        for (int o = 32; o > 0; o >>= 1) f = fminf(f, __shfl_xor(f, o, 64));
        if (tid == 0) out[0] = fminf(f, 1.0f);
    }
}

extern "C" void kernel_launch(void* const* d_in, const int* in_sizes, int n_in,
                              void* d_out, int out_size, void* d_ws, size_t ws_size,
                              hipStream_t stream)
{
    const unsigned char* ia = (const unsigned char*)d_in[0];  // iris_codes_a
    const unsigned char* ma = (const unsigned char*)d_in[1];  // mask_codes_a
    const unsigned char* ib = (const unsigned char*)d_in[2];  // iris_codes_b
    const unsigned char* mb = (const unsigned char*)d_in[3];  // mask_codes_b
    u32* cnt = (u32*)d_ws;                    // [62][32] shadow counters

    hipMemsetAsync(d_ws, 0, 62 * NSH * sizeof(u32), stream);
    hd_main<<<dim3(NBLK), dim3(256), 0, stream>>>(ia, ma, ib, mb, cnt);
    hd_finalize<<<dim3(1), dim3(256), 0, stream>>>(cnt, (float*)d_out);
}

// Round 10
// 43.232 us; speedup vs baseline: 1.2345x; 1.1349x over previous
//
#include <hip/hip_runtime.h>
#include <stdint.h>

typedef unsigned int u32;

#define NACC   31
#define NSHIFT 15
#define ROWB   4096     // bytes per (c,b) row: 2048 positions * 2 planes
#define NBLK   2048     // 2048 blocks * 4 waves = 8192 waves, 1 row each
#define NSH    32       // shadow copies of each counter

// 16 input bytes = positions q..q+7, byte 2i = plane0(q+i), 2i+1 = plane1(q+i).
// Appends 8 bits to P0 (plane0) and P1 (plane1) at bit offset 8t.
// 0/1-byte->bit: (b0|b1<<8|b2<<16|b3<<24)*0x01020408 puts b0..b3 at bits
// 24..27 carry-free.
__device__ __forceinline__ void pack16(uint4 v, u32& P0, u32& P1, int t) {
    const u32 q0 = __byte_perm(v.x, v.y, 0x6420);  // plane0, +0..3
    const u32 q1 = __byte_perm(v.x, v.y, 0x7531);  // plane1, +0..3
    const u32 q2 = __byte_perm(v.z, v.w, 0x6420);  // plane0, +4..7
    const u32 q3 = __byte_perm(v.z, v.w, 0x7531);  // plane1, +4..7
    const u32 n0 = (q0 * 0x01020408u) >> 24;
    const u32 n1 = (q1 * 0x01020408u) >> 24;
    const u32 n2 = (q2 * 0x01020408u) >> 24;
    const u32 n3 = (q3 * 0x01020408u) >> 24;
    P0 |= (n0 | (n2 << 4)) << (8 * t);
    P1 |= (n1 | (n3 << 4)) << (8 * t);
}

// Round-3 core (the 35.8us best) with a lean tail for occupancy.
// One wave per row. Lane l owns positions 32l..32l+31 per plane (u32, bit
// j = position 32l+j); ring = the 64-lane wave (64*32=2048). |s|<=15 < 32 so
// a rotation needs only lane+-1 words (8 shfls/row); the per-word funnel
// shift compiles to a single v_alignbit. Strided per-lane dwordx4 loads
// (lane l -> bytes l*64 + t*16): the 4 t-loads of a lane hit the SAME 64B
// line, so L1 absorbs the stride (measured: R3 FETCH == coalesced variants).
// Tail LDS is 16.9 KB (vs R3's 32.7 KB) and VGPRs are capped via
// __launch_bounds__(256,6): 6 blocks/CU = 24 waves/CU, 1.5x R3's occupancy.
// No device-scope fences (round-4 lesson: per-block __threadfence on CDNA4
// = L2 writeback storm).
__global__ __launch_bounds__(256, 6) void hd_main(
    const unsigned char* __restrict__ ia, const unsigned char* __restrict__ ma,
    const unsigned char* __restrict__ ib, const unsigned char* __restrict__ mb,
    u32* __restrict__ cnt)
{
    const int tid  = threadIdx.x;
    const int lane = tid & 63;
    const int wv   = tid >> 6;
    const int row  = blockIdx.x * 4 + wv;        // 0..8191

    const size_t rb = (size_t)row * ROWB;
    const uint4* pa = (const uint4*)(ia + rb) + lane * 4;
    const uint4* pm = (const uint4*)(ma + rb) + lane * 4;
    const uint4* pb = (const uint4*)(ib + rb) + lane * 4;
    const uint4* pn = (const uint4*)(mb + rb) + lane * 4;

    // ---- load + pack, array by array (compiler batches loads per array) ---
    u32 A0 = 0, A1 = 0, M0 = 0, M1 = 0, B0 = 0, B1 = 0, N0 = 0, N1 = 0;
    {
        uint4 v[4];
#pragma unroll
        for (int t = 0; t < 4; ++t) v[t] = pa[t];
#pragma unroll
        for (int t = 0; t < 4; ++t) pack16(v[t], A0, A1, t);
#pragma unroll
        for (int t = 0; t < 4; ++t) v[t] = pm[t];
#pragma unroll
        for (int t = 0; t < 4; ++t) pack16(v[t], M0, M1, t);
#pragma unroll
        for (int t = 0; t < 4; ++t) v[t] = pb[t];
#pragma unroll
        for (int t = 0; t < 4; ++t) pack16(v[t], B0, B1, t);
#pragma unroll
        for (int t = 0; t < 4; ++t) v[t] = pn[t];
#pragma unroll
        for (int t = 0; t < 4; ++t) pack16(v[t], N0, N1, t);
    }

    u32 acc[NACC];                               // num | den<<16 per shift
#pragma unroll
    for (int j = 0; j < NACC; ++j) acc[j] = 0u;

    const int prevL = (lane + 63) & 63;
    const int nextL = (lane + 1) & 63;
    const u32 pA0 = __shfl(A0, prevL, 64), pA1 = __shfl(A1, prevL, 64);
    const u32 pM0 = __shfl(M0, prevL, 64), pM1 = __shfl(M1, prevL, 64);
    const u32 nA0 = __shfl(A0, nextL, 64), nA1 = __shfl(A1, nextL, 64);
    const u32 nM0 = __shfl(M0, nextL, 64), nM1 = __shfl(M1, nextL, 64);

    {   // s = 0 (j = 15)
        const u32 k0 = M0 & N0, k1 = M1 & N1;
        const u32 nm = __popc((A0 ^ B0) & k0) + __popc((A1 ^ B1) & k1);
        const u32 dn = __popc(k0) + __popc(k1);
        acc[15] += nm | (dn << 16);
    }
#pragma unroll
    for (int s = 1; s <= NSHIFT; ++s) {
        {   // roll right by s: rolled[p] = orig[p-s]  (j = 15+s)
            const u32 ra0 = (A0 << s) | (pA0 >> (32 - s));   // v_alignbit
            const u32 ra1 = (A1 << s) | (pA1 >> (32 - s));
            const u32 rm0 = (M0 << s) | (pM0 >> (32 - s));
            const u32 rm1 = (M1 << s) | (pM1 >> (32 - s));
            const u32 k0 = rm0 & N0, k1 = rm1 & N1;
            const u32 nm = __popc((ra0 ^ B0) & k0) + __popc((ra1 ^ B1) & k1);
            const u32 dn = __popc(k0) + __popc(k1);
            acc[15 + s] += nm | (dn << 16);
        }
        {   // roll left by s: rolled[p] = orig[p+s]   (j = 15-s)
            const u32 ra0 = (A0 >> s) | (nA0 << (32 - s));
            const u32 ra1 = (A1 >> s) | (nA1 << (32 - s));
            const u32 rm0 = (M0 >> s) | (nM0 << (32 - s));
            const u32 rm1 = (M1 >> s) | (nM1 << (32 - s));
            const u32 k0 = rm0 & N0, k1 = rm1 & N1;
            const u32 nm = __popc((ra0 ^ B0) & k0) + __popc((ra1 ^ B1) & k1);
            const u32 dn = __popc(k0) + __popc(k1);
            acc[15 - s] += nm | (dn << 16);
        }
    }

    // ---- per-wave half-butterfly, lean block reduce, shadowed atomics ----
    // per-lane fields <= 64; after 32-xor <= 128; 8-thr/j partials <= 4096.
    __shared__ alignas(16) u32 red[32][132];     // row 31 = dummy, 16.9 KB
#pragma unroll
    for (int j = 0; j < NACC; ++j) acc[j] += __shfl_xor(acc[j], 32, 64);
#pragma unroll
    for (int j = 0; j < NACC; j += 2) {
        const u32 v = (j + 1 < NACC && (lane & 32)) ? acc[j + 1] : acc[j];
        red[j + (lane >> 5)][wv * 32 + (lane & 31)] = v;
    }
    __syncthreads();

    if (tid < 248) {
        const int j = tid >> 3, c = tid & 7;     // 8 threads per counter j
        const uint4* p = (const uint4*)&red[j][c * 16];
        u32 sn = 0, sd = 0;
#pragma unroll
        for (int i = 0; i < 4; ++i) {
            const uint4 v = p[i];
            sn += (v.x & 0xFFFFu) + (v.y & 0xFFFFu) + (v.z & 0xFFFFu) + (v.w & 0xFFFFu);
            sd += (v.x >> 16) + (v.y >> 16) + (v.z >> 16) + (v.w >> 16);
        }
        sn += __shfl_xor(sn, 1, 64); sd += __shfl_xor(sd, 1, 64);
        sn += __shfl_xor(sn, 2, 64); sd += __shfl_xor(sd, 2, 64);
        sn += __shfl_xor(sn, 4, 64); sd += __shfl_xor(sd, 4, 64);
        if (c == 0) {
            const int sh = blockIdx.x & (NSH - 1);
            atomicAdd(&cnt[j * NSH + sh], sn);          // num_j
            atomicAdd(&cnt[(31 + j) * NSH + sh], sd);   // den_j
        }
    }
    // no fence: device-scope atomics + kernel boundary order the finalize.
}

// One block, 256 threads: fold 32 shadows per counter (vector loads),
// 31 divisions, min, clamp to 1.
__global__ void hd_finalize(const u32* __restrict__ cnt, float* __restrict__ out)
{
    __shared__ u32 gathered[62];
    const int tid = threadIdx.x;
    if (tid < 248) {
        const int j = tid >> 2, q = tid & 3;     // 4 threads per counter
        const uint4* p = (const uint4*)&cnt[j * NSH + q * 8];
        const uint4 v0 = p[0], v1 = p[1];
        u32 s = v0.x + v0.y + v0.z + v0.w + v1.x + v1.y + v1.z + v1.w;
        s += __shfl_xor(s, 1, 64);
        s += __shfl_xor(s, 2, 64);
        if (q == 0) gathered[j] = s;
    }
    __syncthreads();
    if (tid < 64) {
        float f = 1.0f;
        if (tid < NACC) f = (float)gathered[tid] / (float)gathered[31 + tid];
#pragma unroll
        for (int o = 32; o > 0; o >>= 1) f = fminf(f, __shfl_xor(f, o, 64));
        if (tid == 0) out[0] = fminf(f, 1.0f);
    }
}

extern "C" void kernel_launch(void* const* d_in, const int* in_sizes, int n_in,
                              void* d_out, int out_size, void* d_ws, size_t ws_size,
                              hipStream_t stream)
{
    const unsigned char* ia = (const unsigned char*)d_in[0];  // iris_codes_a
    const unsigned char* ma = (const unsigned char*)d_in[1];  // mask_codes_a
    const unsigned char* ib = (const unsigned char*)d_in[2];  // iris_codes_b
    const unsigned char* mb = (const unsigned char*)d_in[3];  // mask_codes_b
    u32* cnt = (u32*)d_ws;                    // [62][32] shadow counters

    hipMemsetAsync(d_ws, 0, 62 * NSH * sizeof(u32), stream);
    hd_main<<<dim3(NBLK), dim3(256), 0, stream>>>(ia, ma, ib, mb, cnt);
    hd_finalize<<<dim3(1), dim3(256), 0, stream>>>(cnt, (float*)d_out);
}

// Round 11
// 35.672 us; speedup vs baseline: 1.4962x; 1.2119x over previous
//
#include <hip/hip_runtime.h>
#include <stdint.h>

typedef unsigned long long u64;
typedef unsigned int u32;

#define NACC    31
#define NSHIFT  15
#define NROWS   8192      // 2 * 4096 (c,b) rows
#define ROWB    4096      // bytes per row: 2048 positions * 2 planes
#define NBLK    2048      // 2048 blocks * 4 waves = 8192 waves, 1 row each
#define NSHADOW 32        // shadow copies of the 62 global counters

// De-interleave planes and pack 0/1 bytes to bits.
// v = 16 bytes at positions q..q+7 (byte 2i = plane0(q+i), 2i+1 = plane1(q+i)).
// Appends 8 bits to P0 (plane0) and P1 (plane1) at bit offset 8t.
// Multiply trick: quad bytes b0..b3 (each 0/1): (quad * 0x01020408) has
// b0,b1,b2,b3 at bits 24..27 with no carries (all partial products distinct).
__device__ __forceinline__ void pack16(uint4 v, u32& P0, u32& P1, int t) {
    const u32 q0 = __byte_perm(v.x, v.y, 0x6420);  // plane0, positions q..q+3
    const u32 q1 = __byte_perm(v.x, v.y, 0x7531);  // plane1, positions q..q+3
    const u32 q2 = __byte_perm(v.z, v.w, 0x6420);  // plane0, q+4..q+7
    const u32 q3 = __byte_perm(v.z, v.w, 0x7531);  // plane1, q+4..q+7
    const u32 n0 = (q0 * 0x01020408u) >> 24;
    const u32 n1 = (q1 * 0x01020408u) >> 24;
    const u32 n2 = (q2 * 0x01020408u) >> 24;
    const u32 n3 = (q3 * 0x01020408u) >> 24;
    P0 |= (n0 | (n2 << 4)) << (8 * t);
    P1 |= (n1 | (n3 << 4)) << (8 * t);
}

// One wave per row. Lane l owns positions 32l..32l+31 as one u32 per plane
// (bit j = position 32l+j). Ring = exactly the 64-lane wave (64*32 = 2048).
// Rotation by |s|<=15 needs only lane+-1 neighbors (8 shfls per row).
// Loads are t-interleaved across all 4 arrays so the compiler hoists all 16
// dwordx4 loads (full MLP) — R10 lesson: batching per-array through a reused
// buffer serializes to 4 outstanding loads and regresses 7us. No
// launch_bounds min-waves cap (R10 lesson: ~85-VGPR cap spills).
__global__ __launch_bounds__(256) void hd_main(
    const unsigned char* __restrict__ ia, const unsigned char* __restrict__ ma,
    const unsigned char* __restrict__ ib, const unsigned char* __restrict__ mb,
    u32* __restrict__ cnt)
{
    const int tid  = threadIdx.x;
    const int lane = tid & 63;
    const int row  = blockIdx.x * 4 + (tid >> 6);   // 0..8191

    u32 acc[NACC];                                  // num | den<<16 (each <=64)
#pragma unroll
    for (int j = 0; j < NACC; ++j) acc[j] = 0u;

    const int prevL = (lane + 63) & 63;
    const int nextL = (lane + 1) & 63;

    {
        const uint4* pa = (const uint4*)(ia + (size_t)row * ROWB) + lane * 4;
        const uint4* pm = (const uint4*)(ma + (size_t)row * ROWB) + lane * 4;
        const uint4* pb = (const uint4*)(ib + (size_t)row * ROWB) + lane * 4;
        const uint4* pn = (const uint4*)(mb + (size_t)row * ROWB) + lane * 4;

        u32 A0 = 0, A1 = 0, M0 = 0, M1 = 0, B0 = 0, B1 = 0, N0 = 0, N1 = 0;
#pragma unroll
        for (int t = 0; t < 4; ++t) {
            const uint4 va = pa[t];
            const uint4 vm = pm[t];
            const uint4 vb = pb[t];
            const uint4 vn = pn[t];
            pack16(va, A0, A1, t);
            pack16(vm, M0, M1, t);
            pack16(vb, B0, B1, t);
            pack16(vn, N0, N1, t);
        }

        const u32 pA0 = __shfl(A0, prevL, 64), pA1 = __shfl(A1, prevL, 64);
        const u32 pM0 = __shfl(M0, prevL, 64), pM1 = __shfl(M1, prevL, 64);
        const u32 nA0 = __shfl(A0, nextL, 64), nA1 = __shfl(A1, nextL, 64);
        const u32 nM0 = __shfl(M0, nextL, 64), nM1 = __shfl(M1, nextL, 64);

        {   // s = 0
            const u32 k0 = M0 & N0, k1 = M1 & N1;
            const u32 nm = __popc((A0 ^ B0) & k0) + __popc((A1 ^ B1) & k1);
            const u32 dn = __popc(k0) + __popc(k1);
            acc[15] += nm | (dn << 16);
        }
#pragma unroll
        for (int s = 1; s <= NSHIFT; ++s) {
            {   // roll right by s: rolled[p] = orig[p-s]
                const u32 ra0 = (A0 << s) | (pA0 >> (32 - s));
                const u32 ra1 = (A1 << s) | (pA1 >> (32 - s));
                const u32 rm0 = (M0 << s) | (pM0 >> (32 - s));
                const u32 rm1 = (M1 << s) | (pM1 >> (32 - s));
                const u32 k0 = rm0 & N0, k1 = rm1 & N1;
                const u32 nm = __popc((ra0 ^ B0) & k0) + __popc((ra1 ^ B1) & k1);
                const u32 dn = __popc(k0) + __popc(k1);
                acc[15 + s] += nm | (dn << 16);
            }
            {   // roll left by s: rolled[p] = orig[p+s]
                const u32 ra0 = (A0 >> s) | (nA0 << (32 - s));
                const u32 ra1 = (A1 >> s) | (nA1 << (32 - s));
                const u32 rm0 = (M0 >> s) | (nM0 << (32 - s));
                const u32 rm1 = (M1 >> s) | (nM1 << (32 - s));
                const u32 k0 = rm0 & N0, k1 = rm1 & N1;
                const u32 nm = __popc((ra0 ^ B0) & k0) + __popc((ra1 ^ B1) & k1);
                const u32 dn = __popc(k0) + __popc(k1);
                acc[15 - s] += nm | (dn << 16);
            }
        }
    }

    // Block-wide reduction: 31 KB LDS, one pass, no per-wave butterflies.
    __shared__ alignas(16) u32 red[NACC][264];   // 264 = 256 + 8 pad (banks)
#pragma unroll
    for (int j = 0; j < NACC; ++j) red[j][tid] = acc[j];
    __syncthreads();

    if (tid < 248) {                 // 8 threads per accumulator
        const int j = tid >> 3, c = tid & 7;
        u32 ns = 0, ds = 0;
#pragma unroll
        for (int i = 0; i < 8; ++i) {
            const uint4 v = *(const uint4*)&red[j][c * 32 + i * 4];
            ns += (v.x & 0xFFFFu) + (v.y & 0xFFFFu) + (v.z & 0xFFFFu) + (v.w & 0xFFFFu);
            ds += (v.x >> 16) + (v.y >> 16) + (v.z >> 16) + (v.w >> 16);
        }
#pragma unroll
        for (int o = 1; o < 8; o <<= 1) {
            ns += __shfl_xor(ns, o, 64);
            ds += __shfl_xor(ds, o, 64);
        }
        if (c == 0) {
            const int sh = blockIdx.x & (NSHADOW - 1);
            atomicAdd(&cnt[sh * 62 + j], ns);
            atomicAdd(&cnt[sh * 62 + 31 + j], ds);
        }
    }
    // no fence: device-scope atomics + kernel boundary order the finalize
    // (round-4 lesson: per-block __threadfence on CDNA4 = L2 writeback storm).
}

// One block: fold the 32 shadow copies, 31 divisions, min, clamp to 1.
__global__ void hd_finalize(const u32* __restrict__ cnt, float* __restrict__ out)
{
    __shared__ float fs[64];
    const int tid = threadIdx.x;     // 64 threads
    u32 s = 0;
    if (tid < 62) {
#pragma unroll
        for (int sh = 0; sh < NSHADOW; ++sh) s += cnt[sh * 62 + tid];
    }
    fs[tid < 62 ? tid : 63] = (float)s;
    __syncthreads();
    float f = 1.0f;
    if (tid < NACC) f = fs[tid] / fs[31 + tid];
#pragma unroll
    for (int o = 32; o > 0; o >>= 1) f = fminf(f, __shfl_xor(f, o, 64));
    if (tid == 0) out[0] = fminf(f, 1.0f);
}

extern "C" void kernel_launch(void* const* d_in, const int* in_sizes, int n_in,
                              void* d_out, int out_size, void* d_ws, size_t ws_size,
                              hipStream_t stream)
{
    const unsigned char* ia = (const unsigned char*)d_in[0];  // iris_codes_a
    const unsigned char* ma = (const unsigned char*)d_in[1];  // mask_codes_a
    const unsigned char* ib = (const unsigned char*)d_in[2];  // iris_codes_b
    const unsigned char* mb = (const unsigned char*)d_in[3];  // mask_codes_b
    u32* cnt = (u32*)d_ws;                                    // [32][62]

    hipMemsetAsync(d_ws, 0, NSHADOW * 62 * sizeof(u32), stream);
    hd_main<<<dim3(NBLK), dim3(256), 0, stream>>>(ia, ma, ib, mb, cnt);
    hd_finalize<<<dim3(1), dim3(64), 0, stream>>>(cnt, (float*)d_out);
}